// Round 1
// baseline (940.907 us; speedup 1.0000x reference)
//
#include <hip/hip_runtime.h>

// Problem dims (fixed by the reference)
#define NB 8
#define NC 32      // input channels
#define NCP 33     // channels incl. prepended density
#define NW 256
#define NH 128
#define NX 720
#define NY 361

// Workspace layout (floats): w0t[NB][NX][NW] | w1[NB][NH][NY] | t[NB][NCP][NX][NH]
// total = 1,474,560 + 369,664 + 24,330,240 floats = ~104.7 MB

__global__ __launch_bounds__(256) void rbf_w0_kernel(
    const float* __restrict__ lon_in, const float* __restrict__ lon_out,
    const float* __restrict__ ls, float* __restrict__ w0t)
{
    int idx = blockIdx.x * 256 + threadIdx.x;   // exact grid, no guard needed
    int w = idx & (NW - 1);
    int r = idx >> 8;            // b*NX + x
    int x = r % NX;
    int b = r / NX;
    float l = ls[0];
    float inv = -0.5f / (l * l);
    float d = lon_in[b * NW + w] - lon_out[b * NX + x];
    w0t[idx] = __expf(inv * d * d);   // w0t[b][x][w] (transposed for GEMM A reads)
}

__global__ __launch_bounds__(256) void rbf_w1_kernel(
    const float* __restrict__ lat_in, const float* __restrict__ lat_out,
    const float* __restrict__ ls, float* __restrict__ w1)
{
    int idx = blockIdx.x * 256 + threadIdx.x;   // exact grid
    int y = idx % NY;
    int r = idx / NY;            // b*NH + h
    int h = r % NH;
    int b = r / NH;
    float l = ls[0];
    float inv = -0.5f / (l * l);
    float d = lat_in[b * NH + h] - lat_out[b * NY + y];
    w1[idx] = __expf(inv * d * d);    // w1[b][h][y]
}

// Stage 1: t[b,c,x,h] = sum_w w0t[b,x,w] * wtfix[b,c,w,h]
// 64x64 tile, 256 threads, 4x4 per thread, K-tile 16.
__global__ __launch_bounds__(256) void stage1_kernel(
    const float* __restrict__ w0t, const float* __restrict__ wt,
    float* __restrict__ t)
{
    __shared__ __align__(16) float As[16][68];  // [k][m], +4 pad: conflict-free transpose write
    __shared__ __align__(16) float Bs[16][64];  // [k][n]

    const int bc = blockIdx.z;
    const int b = bc / NCP;
    const int c = bc - b * NCP;
    const int m0 = blockIdx.x * 64;     // x
    const int n0 = blockIdx.y * 64;     // h
    const int tid = threadIdx.x;
    const int tn = tid & 15;            // fast index -> n (h)  => coalesced stores
    const int tm = tid >> 4;            // -> m (x)

    const float* Ap = w0t + (size_t)b * NX * NW;
    const int csrc = (c == 0) ? 0 : (c - 1);
    const float* Bp = wt + (size_t)(b * NC + csrc) * NW * NH;
    const bool densc = (c == 0);

    float acc[4][4];
    #pragma unroll
    for (int i = 0; i < 4; ++i)
        #pragma unroll
        for (int j = 0; j < 4; ++j) acc[i][j] = 0.f;

    const int ak = tid & 15;   // A-load: k
    const int am = tid >> 4;   // A-load: m base (16 rows/pass)
    const int bn = tid & 63;   // B-load: n
    const int bk = tid >> 6;   // B-load: k base (4 rows/pass)

    for (int k0 = 0; k0 < NW; k0 += 16) {
        #pragma unroll
        for (int p = 0; p < 4; ++p) {
            int m = am + p * 16;
            int x = m0 + m;
            As[ak][m] = (x < NX) ? Ap[(size_t)x * NW + k0 + ak] : 0.f;
        }
        #pragma unroll
        for (int p = 0; p < 4; ++p) {
            int k = bk + p * 4;
            float v = Bp[(size_t)(k0 + k) * NH + n0 + bn];
            // density channel: isnan(ch0) ? 0 : 1 ; data channels: isnan ? 0 : v
            v = (v != v) ? 0.f : (densc ? 1.f : v);
            Bs[k][bn] = v;
        }
        __syncthreads();
        #pragma unroll
        for (int k = 0; k < 16; ++k) {
            float4 af = *(const float4*)&As[k][tm * 4];
            float4 bf = *(const float4*)&Bs[k][tn * 4];
            float av[4] = {af.x, af.y, af.z, af.w};
            float bv[4] = {bf.x, bf.y, bf.z, bf.w};
            #pragma unroll
            for (int i = 0; i < 4; ++i)
                #pragma unroll
                for (int j = 0; j < 4; ++j)
                    acc[i][j] += av[i] * bv[j];
        }
        __syncthreads();
    }

    float* Cp = t + (size_t)bc * NX * NH;
    #pragma unroll
    for (int i = 0; i < 4; ++i) {
        int x = m0 + tm * 4 + i;
        if (x < NX) {
            float4 v = make_float4(acc[i][0], acc[i][1], acc[i][2], acc[i][3]);
            *(float4*)&Cp[(size_t)x * NH + n0 + tn * 4] = v;   // contiguous across tn
        }
    }
}

// Stage 2: out_raw[b,c,x,y] = sum_h t[b,c,x,h] * w1[b,h,y]
__global__ __launch_bounds__(256) void stage2_kernel(
    const float* __restrict__ t, const float* __restrict__ w1,
    float* __restrict__ out)
{
    __shared__ __align__(16) float As[16][68];
    __shared__ __align__(16) float Bs[16][64];

    const int bc = blockIdx.z;
    const int b = bc / NCP;
    const int m0 = blockIdx.x * 64;     // x
    const int n0 = blockIdx.y * 64;     // y
    const int tid = threadIdx.x;
    const int tn = tid & 15;
    const int tm = tid >> 4;

    const float* Ap = t + (size_t)bc * NX * NH;
    const float* Bp = w1 + (size_t)b * NH * NY;

    float acc[4][4];
    #pragma unroll
    for (int i = 0; i < 4; ++i)
        #pragma unroll
        for (int j = 0; j < 4; ++j) acc[i][j] = 0.f;

    const int ak = tid & 15;
    const int am = tid >> 4;
    const int bn = tid & 63;
    const int bk = tid >> 6;

    for (int k0 = 0; k0 < NH; k0 += 16) {
        #pragma unroll
        for (int p = 0; p < 4; ++p) {
            int m = am + p * 16;
            int x = m0 + m;
            As[ak][m] = (x < NX) ? Ap[(size_t)x * NH + k0 + ak] : 0.f;
        }
        #pragma unroll
        for (int p = 0; p < 4; ++p) {
            int k = bk + p * 4;
            int y = n0 + bn;
            Bs[k][bn] = (y < NY) ? Bp[(size_t)(k0 + k) * NY + y] : 0.f;
        }
        __syncthreads();
        #pragma unroll
        for (int k = 0; k < 16; ++k) {
            float4 af = *(const float4*)&As[k][tm * 4];
            float4 bf = *(const float4*)&Bs[k][tn * 4];
            float av[4] = {af.x, af.y, af.z, af.w};
            float bv[4] = {bf.x, bf.y, bf.z, bf.w};
            #pragma unroll
            for (int i = 0; i < 4; ++i)
                #pragma unroll
                for (int j = 0; j < 4; ++j)
                    acc[i][j] += av[i] * bv[j];
        }
        __syncthreads();
    }

    float* Cp = out + (size_t)bc * NX * NY;
    #pragma unroll
    for (int i = 0; i < 4; ++i) {
        int x = m0 + tm * 4 + i;
        if (x < NX) {
            #pragma unroll
            for (int j = 0; j < 4; ++j) {
                int y = n0 + tn * 4 + j;
                if (y < NY) Cp[(size_t)x * NY + y] = acc[i][j];
            }
        }
    }
}

// Epilogue: channels 1..32 /= clip(density, 1e-6, 1e5), in place.
__global__ __launch_bounds__(256) void epilogue_kernel(float* __restrict__ out)
{
    int idx = blockIdx.x * 256 + threadIdx.x;
    if (idx >= NB * NC * NX * NY) return;
    int y = idx % NY;
    int r = idx / NY;
    int x = r % NX;
    r /= NX;
    int c = r % NC;      // 0..31 -> output channel c+1
    int b = r / NC;
    const size_t plane = (size_t)NX * NY;
    size_t dofs = (size_t)(b * NCP) * plane + (size_t)x * NY + y;
    float dv = out[dofs];
    dv = fminf(fmaxf(dv, 1e-6f), 1e5f);
    size_t oofs = (size_t)(b * NCP + c + 1) * plane + (size_t)x * NY + y;
    out[oofs] = out[oofs] / dv;
}

extern "C" void kernel_launch(void* const* d_in, const int* in_sizes, int n_in,
                              void* d_out, int out_size, void* d_ws, size_t ws_size,
                              hipStream_t stream)
{
    const float* wt      = (const float*)d_in[0];
    const float* lon_in  = (const float*)d_in[1];
    const float* lat_in  = (const float*)d_in[2];
    const float* lon_out = (const float*)d_in[3];
    const float* lat_out = (const float*)d_in[4];
    const float* ls      = (const float*)d_in[5];
    float* out = (float*)d_out;

    float* w0t = (float*)d_ws;
    float* w1  = w0t + (size_t)NB * NX * NW;
    float* t   = w1  + (size_t)NB * NH * NY;

    rbf_w0_kernel<<<(NB * NX * NW) / 256, 256, 0, stream>>>(lon_in, lon_out, ls, w0t);
    rbf_w1_kernel<<<(NB * NH * NY) / 256, 256, 0, stream>>>(lat_in, lat_out, ls, w1);

    dim3 g1((NX + 63) / 64, NH / 64, NB * NCP);      // 12 x 2 x 264
    stage1_kernel<<<g1, 256, 0, stream>>>(w0t, wt, t);

    dim3 g2((NX + 63) / 64, (NY + 63) / 64, NB * NCP); // 12 x 6 x 264
    stage2_kernel<<<g2, 256, 0, stream>>>(t, w1, out);

    int tot = NB * NC * NX * NY;
    epilogue_kernel<<<(tot + 255) / 256, 256, 0, stream>>>(out);
}

// Round 2
// 467.597 us; speedup vs baseline: 2.0122x; 2.0122x over previous
//
#include <hip/hip_runtime.h>

// Dims
#define NB 8
#define NC 32
#define NCP 33
#define NW 256
#define NH 128
#define NX 720
#define NY 361

typedef __attribute__((ext_vector_type(8))) short  short8;
typedef __attribute__((ext_vector_type(4))) float  f32x4;

// fp32 -> bf16 round-to-nearest-even
static __device__ __forceinline__ unsigned short f2bf(float f) {
    union { float f; unsigned int u; } v; v.f = f;
    unsigned int r = (v.u + 0x7FFFu + ((v.u >> 16) & 1u)) >> 16;
    return (unsigned short)r;
}

// K1: w0t[b][x][w] bf16  (A-operand layout for stage1: m=x, k=w contiguous)
__global__ __launch_bounds__(256) void rbf_w0_kernel(
    const float* __restrict__ lon_in, const float* __restrict__ lon_out,
    const float* __restrict__ ls, unsigned short* __restrict__ w0t)
{
    int idx = blockIdx.x * 256 + threadIdx.x;   // exact grid: 8*720*256
    int w = idx & (NW - 1);
    int r = idx >> 8;
    int x = r % NX;
    int b = r / NX;
    float l = ls[0];
    float inv = -0.5f / (l * l);
    float d = lon_in[b * NW + w] - lon_out[b * NX + x];
    w0t[idx] = f2bf(__expf(inv * d * d));
}

// K2: w1t[b][y][h] bf16  (B-operand layout for stage2: n=y rows, k=h contiguous)
__global__ __launch_bounds__(256) void rbf_w1_kernel(
    const float* __restrict__ lat_in, const float* __restrict__ lat_out,
    const float* __restrict__ ls, unsigned short* __restrict__ w1t)
{
    int idx = blockIdx.x * 256 + threadIdx.x;   // exact grid: 8*361*128
    int h = idx & (NH - 1);
    int r = idx >> 7;
    int y = r % NY;
    int b = r / NY;
    float l = ls[0];
    float inv = -0.5f / (l * l);
    float d = lat_in[b * NH + h] - lat_out[b * NY + y];
    w1t[idx] = f2bf(__expf(inv * d * d));
}

// K3: wtT[b][c(33)][h(128)][w(256)] bf16 — transposed, NaN-fixed, c=0 = density mask.
// Block: one (b,c) x one 64-wide w-tile; LDS transpose.
__global__ __launch_bounds__(256) void prep_wtT_kernel(
    const float* __restrict__ wt, unsigned short* __restrict__ wtT)
{
    __shared__ float tile[64 * 129];
    const int bc = blockIdx.z;
    const int b = bc / NCP;
    const int c = bc - b * NCP;
    const int w0 = blockIdx.x * 64;
    const bool dens = (c == 0);
    const float* src = wt + ((size_t)b * NC + (dens ? 0 : (c - 1))) * (NW * NH);

    const int r4 = threadIdx.x >> 5;   // 0..7
    const int c4 = threadIdx.x & 31;   // float4 col
    #pragma unroll
    for (int p = 0; p < 8; ++p) {
        int r = r4 + p * 8;
        float4 v = *(const float4*)&src[(size_t)(w0 + r) * NH + c4 * 4];
        float o0 = (v.x != v.x) ? 0.f : (dens ? 1.f : v.x);
        float o1 = (v.y != v.y) ? 0.f : (dens ? 1.f : v.y);
        float o2 = (v.z != v.z) ? 0.f : (dens ? 1.f : v.z);
        float o3 = (v.w != v.w) ? 0.f : (dens ? 1.f : v.w);
        float* tp = &tile[r * 129 + c4 * 4];
        tp[0] = o0; tp[1] = o1; tp[2] = o2; tp[3] = o3;
    }
    __syncthreads();

    unsigned short* dst = wtT + (size_t)bc * (NH * NW);
    #pragma unroll
    for (int p = 0; p < 4; ++p) {
        int ch = threadIdx.x + p * 256;
        int wc = ch & 7;          // which 8-w chunk in this 64-w tile
        int h  = ch >> 3;         // 0..127
        unsigned int u[4];
        #pragma unroll
        for (int j = 0; j < 4; ++j) {
            unsigned int lo = f2bf(tile[(wc * 8 + 2 * j    ) * 129 + h]);
            unsigned int hi = f2bf(tile[(wc * 8 + 2 * j + 1) * 129 + h]);
            u[j] = lo | (hi << 16);
        }
        uint4 q = make_uint4(u[0], u[1], u[2], u[3]);
        *(uint4*)&dst[(size_t)h * NW + w0 + wc * 8] = q;
    }
}

// Stage 1 MFMA: t[bc][x][h] = sum_w w0t[b][x][w] * wtT[bc][h][w]
// grid (12, 2, 264); 64x64 tile, BK=64, 4 waves x (32x32).
__global__ __launch_bounds__(256) void stage1_mfma(
    const unsigned short* __restrict__ w0t,
    const unsigned short* __restrict__ wtT,
    unsigned short* __restrict__ t)
{
    __shared__ __align__(16) unsigned short As[64 * 88];
    __shared__ __align__(16) unsigned short Bs[64 * 88];

    const int bc = blockIdx.z;
    const int b  = bc / NCP;
    const int x0 = blockIdx.x * 64;
    const int h0 = blockIdx.y * 64;
    const int tid  = threadIdx.x;
    const int lane = tid & 63;
    const int wv   = tid >> 6;
    const int q    = lane >> 4;
    const int ln   = lane & 15;
    const int mw   = (wv & 1) * 32;
    const int nw   = (wv >> 1) * 32;

    const unsigned short* Ap = w0t + (size_t)b * NX * NW;
    const unsigned short* Bp = wtT + (size_t)bc * NH * NW;

    f32x4 acc[2][2];
    #pragma unroll
    for (int i = 0; i < 2; ++i)
        #pragma unroll
        for (int j = 0; j < 2; ++j)
            acc[i][j] = (f32x4){0.f, 0.f, 0.f, 0.f};

    const int r_ld  = tid >> 3;   // 0..31
    const int cc_ld = tid & 7;

    for (int k0 = 0; k0 < NW; k0 += 64) {
        #pragma unroll
        for (int p = 0; p < 2; ++p) {
            int r = r_ld + p * 32;
            int xr = x0 + r; if (xr > NX - 1) xr = NX - 1;
            *(uint4*)&As[r * 88 + cc_ld * 8] =
                *(const uint4*)&Ap[(size_t)xr * NW + k0 + cc_ld * 8];
            *(uint4*)&Bs[r * 88 + cc_ld * 8] =
                *(const uint4*)&Bp[(size_t)(h0 + r) * NW + k0 + cc_ld * 8];
        }
        __syncthreads();
        #pragma unroll
        for (int ki = 0; ki < 2; ++ki) {
            const int ko = ki * 32 + q * 8;
            short8 a0 = *(const short8*)&As[(mw      + ln) * 88 + ko];
            short8 a1 = *(const short8*)&As[(mw + 16 + ln) * 88 + ko];
            short8 b0 = *(const short8*)&Bs[(nw      + ln) * 88 + ko];
            short8 b1 = *(const short8*)&Bs[(nw + 16 + ln) * 88 + ko];
            acc[0][0] = __builtin_amdgcn_mfma_f32_16x16x32_bf16(a0, b0, acc[0][0], 0, 0, 0);
            acc[0][1] = __builtin_amdgcn_mfma_f32_16x16x32_bf16(a0, b1, acc[0][1], 0, 0, 0);
            acc[1][0] = __builtin_amdgcn_mfma_f32_16x16x32_bf16(a1, b0, acc[1][0], 0, 0, 0);
            acc[1][1] = __builtin_amdgcn_mfma_f32_16x16x32_bf16(a1, b1, acc[1][1], 0, 0, 0);
        }
        __syncthreads();
    }

    unsigned short* Cp = t + (size_t)bc * NX * NH;
    #pragma unroll
    for (int mi = 0; mi < 2; ++mi)
        #pragma unroll
        for (int reg = 0; reg < 4; ++reg) {
            int x = x0 + mw + mi * 16 + q * 4 + reg;
            if (x < NX) {
                size_t rowo = (size_t)x * NH;
                #pragma unroll
                for (int ni = 0; ni < 2; ++ni) {
                    int h = h0 + nw + ni * 16 + ln;
                    Cp[rowo + h] = f2bf(acc[mi][ni][reg]);
                }
            }
        }
}

// Stage 2 MFMA: ee[bc][x][y] = sum_h t[bc][x][h] * w1t[b][y][h]
// DIV=false: c=0 (density plane), grid (12,6,8).
// DIV=true : c=1..32, divide by clipped dens, grid (12,6,256).
template <bool DIV>
__global__ __launch_bounds__(256) void stage2_mfma(
    const unsigned short* __restrict__ t,
    const unsigned short* __restrict__ w1t,
    float* __restrict__ out)
{
    __shared__ __align__(16) unsigned short As[64 * 88];
    __shared__ __align__(16) unsigned short Bs[64 * 88];

    int b, c;
    if (DIV) { b = blockIdx.z >> 5; c = 1 + (blockIdx.z & 31); }
    else     { b = blockIdx.z;      c = 0; }
    const int bc = b * NCP + c;
    const int x0 = blockIdx.x * 64;
    const int y0 = blockIdx.y * 64;
    const int tid  = threadIdx.x;
    const int lane = tid & 63;
    const int wv   = tid >> 6;
    const int q    = lane >> 4;
    const int ln   = lane & 15;
    const int mw   = (wv & 1) * 32;
    const int nw   = (wv >> 1) * 32;

    const unsigned short* Ap = t + (size_t)bc * NX * NH;
    const unsigned short* Bp = w1t + (size_t)b * NY * NH;

    f32x4 acc[2][2];
    #pragma unroll
    for (int i = 0; i < 2; ++i)
        #pragma unroll
        for (int j = 0; j < 2; ++j)
            acc[i][j] = (f32x4){0.f, 0.f, 0.f, 0.f};

    const int r_ld  = tid >> 3;
    const int cc_ld = tid & 7;

    for (int k0 = 0; k0 < NH; k0 += 64) {
        #pragma unroll
        for (int p = 0; p < 2; ++p) {
            int r = r_ld + p * 32;
            int xr = x0 + r; if (xr > NX - 1) xr = NX - 1;
            int yr = y0 + r; if (yr > NY - 1) yr = NY - 1;
            *(uint4*)&As[r * 88 + cc_ld * 8] =
                *(const uint4*)&Ap[(size_t)xr * NH + k0 + cc_ld * 8];
            *(uint4*)&Bs[r * 88 + cc_ld * 8] =
                *(const uint4*)&Bp[(size_t)yr * NH + k0 + cc_ld * 8];
        }
        __syncthreads();
        #pragma unroll
        for (int ki = 0; ki < 2; ++ki) {
            const int ko = ki * 32 + q * 8;
            short8 a0 = *(const short8*)&As[(mw      + ln) * 88 + ko];
            short8 a1 = *(const short8*)&As[(mw + 16 + ln) * 88 + ko];
            short8 b0 = *(const short8*)&Bs[(nw      + ln) * 88 + ko];
            short8 b1 = *(const short8*)&Bs[(nw + 16 + ln) * 88 + ko];
            acc[0][0] = __builtin_amdgcn_mfma_f32_16x16x32_bf16(a0, b0, acc[0][0], 0, 0, 0);
            acc[0][1] = __builtin_amdgcn_mfma_f32_16x16x32_bf16(a0, b1, acc[0][1], 0, 0, 0);
            acc[1][0] = __builtin_amdgcn_mfma_f32_16x16x32_bf16(a1, b0, acc[1][0], 0, 0, 0);
            acc[1][1] = __builtin_amdgcn_mfma_f32_16x16x32_bf16(a1, b1, acc[1][1], 0, 0, 0);
        }
        __syncthreads();
    }

    const size_t plane = (size_t)NX * NY;
    float* Cp = out + (size_t)bc * plane;
    const float* Dp = out + (size_t)(b * NCP) * plane;   // density plane (c=0)

    #pragma unroll
    for (int mi = 0; mi < 2; ++mi)
        #pragma unroll
        for (int reg = 0; reg < 4; ++reg) {
            int x = x0 + mw + mi * 16 + q * 4 + reg;
            if (x < NX) {
                size_t rowo = (size_t)x * NY;
                #pragma unroll
                for (int ni = 0; ni < 2; ++ni) {
                    int y = y0 + nw + ni * 16 + ln;
                    if (y < NY) {
                        float val = acc[mi][ni][reg];
                        if (DIV) {
                            float dv = Dp[rowo + y];
                            dv = fminf(fmaxf(dv, 1e-6f), 1e5f);
                            val /= dv;
                        }
                        Cp[rowo + y] = val;
                    }
                }
            }
        }
}

extern "C" void kernel_launch(void* const* d_in, const int* in_sizes, int n_in,
                              void* d_out, int out_size, void* d_ws, size_t ws_size,
                              hipStream_t stream)
{
    const float* wt      = (const float*)d_in[0];
    const float* lon_in  = (const float*)d_in[1];
    const float* lat_in  = (const float*)d_in[2];
    const float* lon_out = (const float*)d_in[3];
    const float* lat_out = (const float*)d_in[4];
    const float* ls      = (const float*)d_in[5];
    float* out = (float*)d_out;

    // Workspace (ushort elements): w0t | w1t | wtT | t  — ~69.7 MB total
    unsigned short* w0t = (unsigned short*)d_ws;
    unsigned short* w1t = w0t + (size_t)NB * NX * NW;            // 1,474,560
    unsigned short* wtT = w1t + (size_t)NB * NY * NH;            // +369,664
    unsigned short* t   = wtT + (size_t)NB * NCP * NH * NW;      // +8,650,752

    rbf_w0_kernel<<<(NB * NX * NW) / 256, 256, 0, stream>>>(lon_in, lon_out, ls, w0t);
    rbf_w1_kernel<<<(NB * NY * NH) / 256, 256, 0, stream>>>(lat_in, lat_out, ls, w1t);

    dim3 g3(4, 1, NB * NCP);                 // 4 w-tiles x 264 (b,c)
    prep_wtT_kernel<<<g3, 256, 0, stream>>>(wt, wtT);

    dim3 g1(12, 2, NB * NCP);                // x-tiles, h-tiles, (b,c)
    stage1_mfma<<<g1, 256, 0, stream>>>(w0t, wtT, t);

    dim3 g2a(12, 6, NB);                     // density plane first
    stage2_mfma<false><<<g2a, 256, 0, stream>>>(t, w1t, out);

    dim3 g2b(12, 6, NB * NC);                // data channels, fused division
    stage2_mfma<true><<<g2b, 256, 0, stream>>>(t, w1t, out);
}